// Round 2
// baseline (566.962 us; speedup 1.0000x reference)
//
#include <hip/hip_runtime.h>
#include <hip/hip_bf16.h>

#define DEV __device__ __forceinline__

namespace {

constexpr int D     = 1024;
constexpr int F     = 2048;
constexpr int E     = 8;
constexpr int TWO_F = 2 * F;

typedef short bf16x8 __attribute__((ext_vector_type(8)));
typedef float f32x4  __attribute__((ext_vector_type(4)));

DEV unsigned short f32_to_bf16(float f) {
  unsigned int u = __builtin_bit_cast(unsigned int, f);
  u += 0x7fffu + ((u >> 16) & 1u);   // RNE
  return (unsigned short)(u >> 16);
}

// async global->LDS, 16B per lane; LDS dest is wave-uniform base + lane*16 implicit
DEV void load_lds16(const void* g, void* l) {
  __builtin_amdgcn_global_load_lds((const __attribute__((address_space(1))) void*)g,
                                   (__attribute__((address_space(3))) void*)l, 16, 0, 0);
}

// XOR-swizzled fragment address: LDS[row][c] holds global chunk c ^ (row&7).
DEV const bf16x8* frag_addr(const unsigned short* S, int row, int kk, int quad) {
  int cl = (((kk >> 3) + quad) ^ (row & 7));
  return (const bf16x8*)(S + row * 64 + cl * 8);
}

__global__ void zero_kernel(float* __restrict__ p, int n4) {
  int i = blockIdx.x * 256 + threadIdx.x;
  if (i < n4) ((float4*)p)[i] = make_float4(0.f, 0.f, 0.f, 0.f);
}

// One fused fp32->bf16 conversion over x, W1, W2 (sizes are multiples of 2048 elems).
__global__ void cvt_all_kernel(const float* __restrict__ x, const float* __restrict__ W1,
                               const float* __restrict__ W2,
                               unsigned short* __restrict__ xb, unsigned short* __restrict__ W1b,
                               unsigned short* __restrict__ W2b,
                               long long nx, long long n1) {
  long long i = (long long)(blockIdx.x * 256 + threadIdx.x) * 8;
  const float* src;
  unsigned short* dst;
  long long off;
  if (i < nx)            { src = x;  dst = xb;  off = i; }
  else if (i < nx + n1)  { src = W1; dst = W1b; off = i - nx; }
  else                   { src = W2; dst = W2b; off = i - nx - n1; }
  float4 a = *(const float4*)(src + off);
  float4 b = *(const float4*)(src + off + 4);
  uint4 o;
  o.x = (unsigned)f32_to_bf16(a.x) | ((unsigned)f32_to_bf16(a.y) << 16);
  o.y = (unsigned)f32_to_bf16(a.z) | ((unsigned)f32_to_bf16(a.w) << 16);
  o.z = (unsigned)f32_to_bf16(b.x) | ((unsigned)f32_to_bf16(b.y) << 16);
  o.w = (unsigned)f32_to_bf16(b.z) | ((unsigned)f32_to_bf16(b.w) << 16);
  *(uint4*)(dst + off) = o;
}

// Router: one wave per token; fp32 dot over D=1024, top-2 + softmax. NO atomics.
__global__ void router_kernel(const float* __restrict__ x, const float* __restrict__ Wr,
                              const float* __restrict__ temp,
                              int* __restrict__ topk_idx, float* __restrict__ topk_gate, int T) {
  int wid  = blockIdx.x * 4 + (threadIdx.x >> 6);
  int lane = threadIdx.x & 63;
  if (wid >= T) return;
  const float* xr = x + (size_t)wid * D;
  float acc[E];
#pragma unroll
  for (int e = 0; e < E; ++e) acc[e] = 0.f;
  int base = lane * 16;
#pragma unroll
  for (int u = 0; u < 4; ++u) {
    float4 xv = *(const float4*)(xr + base + u * 4);
#pragma unroll
    for (int e = 0; e < E; ++e) {
      float4 wv = *(const float4*)(Wr + e * D + base + u * 4);
      acc[e] += xv.x * wv.x + xv.y * wv.y + xv.z * wv.z + xv.w * wv.w;
    }
  }
#pragma unroll
  for (int e = 0; e < E; ++e) {
    float v = acc[e];
#pragma unroll
    for (int off = 32; off > 0; off >>= 1) v += __shfl_xor(v, off, 64);
    acc[e] = v;
  }
  if (lane == 0) {
    float inv = 1.0f / temp[0];
    float l[E];
#pragma unroll
    for (int e = 0; e < E; ++e) l[e] = acc[e] * inv;
    int e0 = 0;
#pragma unroll
    for (int e = 1; e < E; ++e) if (l[e] > l[e0]) e0 = e;   // first-index tie-break like top_k
    int e1 = (e0 == 0) ? 1 : 0;
#pragma unroll
    for (int e = 0; e < E; ++e) if (e != e0 && l[e] > l[e1]) e1 = e;
    float dlt = l[e1] - l[e0];
    float ed  = __expf(dlt);
    topk_idx[2 * wid]      = e0;
    topk_idx[2 * wid + 1]  = e1;
    topk_gate[2 * wid]     = 1.f / (1.f + ed);
    topk_gate[2 * wid + 1] = ed / (1.f + ed);
  }
}

// Single block, 1024 threads: histogram (LDS atomics) -> scan -> compacted expert lists.
__global__ __launch_bounds__(1024)
void assign_kernel(const int* __restrict__ topk_idx, const float* __restrict__ topk_gate,
                   int* __restrict__ counts, int* __restrict__ offsets,
                   int* __restrict__ row_token, float* __restrict__ row_gate, int T) {
  __shared__ int hist[E];
  __shared__ int cur[E];
  const int tid = threadIdx.x;
  if (tid < E) hist[tid] = 0;
  __syncthreads();
  for (int t = tid; t < T; t += 1024) {
    atomicAdd(&hist[topk_idx[2 * t]], 1);
    atomicAdd(&hist[topk_idx[2 * t + 1]], 1);
  }
  __syncthreads();
  if (tid == 0) {
    int s = 0;
    for (int e = 0; e < E; ++e) {
      int c = hist[e];
      counts[e]  = c;
      offsets[e] = s;
      cur[e]     = s;
      s += c;
    }
  }
  __syncthreads();
  for (int t = tid; t < T; t += 1024) {
#pragma unroll
    for (int s = 0; s < 2; ++s) {
      int e = topk_idx[2 * t + s];
      int p = atomicAdd(&cur[e], 1);
      row_token[p] = t;
      row_gate[p]  = topk_gate[2 * t + s];
    }
  }
}

// ---------------------------------------------------------------------------
// GEMM template: BM=128 (rows), BN=256 (B-rows), BK=64, 512 thr = 8 waves
// (2M x 4N, 64x64 per wave, acc[4][4]).  3 LDS buffers (A 16KB + B 32KB each,
// 145 KB total -> 1 block/CU), 2-K-tile-deep pipeline with counted vmcnt
// (6 gload_lds / wave / K-tile; steady gate vmcnt(12)), raw s_barrier
// (no drain), setprio(1) around the MFMA cluster.
// Race-freedom: barrier#2 of tile t-1 orders all reads of buf[(t+2)%3] before
// any stage-issue for t+2; per-wave vmcnt + barrier#1 orders landings before
// reads of tile t.  Barrier pairing is by ordinal; control flow around all
// barriers is block-uniform.
// ---------------------------------------------------------------------------

// GEMM1: h = gather(x) @ W1[e]^T; fused SwiGLU -> a_buf (bf16).
// Bs row grouping per 64: [h1 c0..31 | h2 c0..31]; acc[i][j] pairs acc[i][j+2].
__global__ __launch_bounds__(512, 2)
void gemm1_kernel(const unsigned short* __restrict__ xb,
                  const unsigned short* __restrict__ W1b,
                  const float* __restrict__ b1,
                  const int* __restrict__ counts, const int* __restrict__ offsets,
                  const int* __restrict__ row_token,
                  unsigned short* __restrict__ a_buf) {
  const int e  = blockIdx.z;
  const int m0 = blockIdx.y * 128;
  const int bx = blockIdx.x;                 // a-cols [bx*128, bx*128+128)
  const int cnt = counts[e];
  if (m0 >= cnt) return;
  const int pairBase = offsets[e];

  __shared__ __align__(16) unsigned short As[3][128 * 64];
  __shared__ __align__(16) unsigned short Bs[3][256 * 64];
  __shared__ int tokS[128];

  const int tid = threadIdx.x;
  if (tid < 128) {
    int r = m0 + tid;
    tokS[tid] = (r < cnt) ? row_token[pairBase + r] : row_token[pairBase];  // clamp: safe garbage
  }
  __syncthreads();

  const int lane = tid & 63;
  const int wave = tid >> 6;
  const int quad = lane >> 4;
  const int l16  = lane & 15;
  const int lr   = lane >> 3;          // 0..7 row-in-8 for staging
  const int lc   = lane & 7;           // chunk slot
  const int sw   = lc ^ lr;            // pre-swizzled global chunk
  const int wr   = wave >> 2;          // 0..1
  const int wc   = wave & 3;           // 0..3

  const unsigned short* W1e = W1b + (size_t)e * TWO_F * D;
  const unsigned short* aSrc[2];
  const unsigned short* bSrc[4];
#pragma unroll
  for (int i = 0; i < 2; ++i) {
    int rA = i * 64 + wave * 8 + lr;
    aSrc[i] = xb + (size_t)tokS[rA] * D + sw * 8;
  }
#pragma unroll
  for (int i = 0; i < 4; ++i) {
    int rB = i * 64 + wave * 8 + lr;
    int wrow = ((rB >> 5) & 1) * F + bx * 128 + (rB >> 6) * 32 + (rB & 31);
    bSrc[i] = W1e + (size_t)wrow * D + sw * 8;
  }

  auto stage = [&](int t, int b) {
#pragma unroll
    for (int i = 0; i < 2; ++i)
      load_lds16(aSrc[i] + t * 64, &As[b][(i * 64 + wave * 8) * 64]);
#pragma unroll
    for (int i = 0; i < 4; ++i)
      load_lds16(bSrc[i] + t * 64, &Bs[b][(i * 64 + wave * 8) * 64]);
  };

  f32x4 acc[4][4];
#pragma unroll
  for (int i = 0; i < 4; ++i)
#pragma unroll
    for (int j = 0; j < 4; ++j) acc[i][j] = (f32x4){0.f, 0.f, 0.f, 0.f};

  constexpr int NT = D / 64;   // 16
  stage(0, 0);
  stage(1, 1);
  int buf = 0;
  for (int t = 0; t < NT; ++t) {
    if (t + 2 < NT) {
      int nb = buf + 2; if (nb >= 3) nb -= 3;
      stage(t + 2, nb);
      asm volatile("s_waitcnt vmcnt(12)" ::: "memory");
    } else if (t + 1 < NT) {
      asm volatile("s_waitcnt vmcnt(6)" ::: "memory");
    } else {
      asm volatile("s_waitcnt vmcnt(0)" ::: "memory");
    }
    __builtin_amdgcn_sched_barrier(0);
    __builtin_amdgcn_s_barrier();          // all waves' tile-t loads landed
    __builtin_amdgcn_sched_barrier(0);
    const unsigned short* Ab = As[buf];
    const unsigned short* Bb = Bs[buf];
    bf16x8 a0[4], b0[4], a1[4], b1f[4];
#pragma unroll
    for (int i = 0; i < 4; ++i) a0[i]  = *frag_addr(Ab, wr * 64 + i * 16 + l16, 0,  quad);
#pragma unroll
    for (int j = 0; j < 4; ++j) b0[j]  = *frag_addr(Bb, wc * 64 + j * 16 + l16, 0,  quad);
#pragma unroll
    for (int i = 0; i < 4; ++i) a1[i]  = *frag_addr(Ab, wr * 64 + i * 16 + l16, 32, quad);
#pragma unroll
    for (int j = 0; j < 4; ++j) b1f[j] = *frag_addr(Bb, wc * 64 + j * 16 + l16, 32, quad);
    __builtin_amdgcn_s_setprio(1);
#pragma unroll
    for (int i = 0; i < 4; ++i)
#pragma unroll
      for (int j = 0; j < 4; ++j)
        acc[i][j] = __builtin_amdgcn_mfma_f32_16x16x32_bf16(a0[i], b0[j], acc[i][j], 0, 0, 0);
#pragma unroll
    for (int i = 0; i < 4; ++i)
#pragma unroll
      for (int j = 0; j < 4; ++j)
        acc[i][j] = __builtin_amdgcn_mfma_f32_16x16x32_bf16(a1[i], b1f[j], acc[i][j], 0, 0, 0);
    __builtin_amdgcn_s_setprio(0);
    __builtin_amdgcn_sched_barrier(0);
    __builtin_amdgcn_s_barrier();          // reads of buf done -> free for t+3
    ++buf; if (buf >= 3) buf = 0;
  }

  // Epilogue: a = h1 * silu(h2); acc[i][j] (j=0,1 -> h1) pairs acc[i][j+2] (h2).
#pragma unroll
  for (int i = 0; i < 4; ++i) {
    int rb = wr * 64 + i * 16 + quad * 4;
#pragma unroll
    for (int j = 0; j < 2; ++j) {
      int col = bx * 128 + wc * 32 + j * 16 + l16;
      float bh1 = b1[e * TWO_F + col];
      float bh2 = b1[e * TWO_F + F + col];
#pragma unroll
      for (int rg = 0; rg < 4; ++rg) {
        int r = rb + rg;
        if (m0 + r < cnt) {
          float h1 = acc[i][j][rg] + bh1;
          float h2 = acc[i][j + 2][rg] + bh2;
          float a  = h1 * (h2 / (1.f + __expf(-h2)));
          a_buf[(size_t)(pairBase + m0 + r) * F + col] = f32_to_bf16(a);
        }
      }
    }
  }
}

// GEMM2: y = a @ W2[e]^T ; out[token] += gate * (y + b2)  (fp32 atomics, out pre-zeroed)
__global__ __launch_bounds__(512, 2)
void gemm2_kernel(const unsigned short* __restrict__ a_buf,
                  const unsigned short* __restrict__ W2b,
                  const float* __restrict__ b2,
                  const int* __restrict__ counts, const int* __restrict__ offsets,
                  const int* __restrict__ row_token, const float* __restrict__ row_gate,
                  float* __restrict__ out, int totalPairs) {
  const int e  = blockIdx.z;
  const int m0 = blockIdx.y * 128;
  const int bx = blockIdx.x;                 // out cols [bx*256, bx*256+256)
  const int cnt = counts[e];
  if (m0 >= cnt) return;
  const int pairBase = offsets[e];

  __shared__ __align__(16) unsigned short As[3][128 * 64];
  __shared__ __align__(16) unsigned short Bs[3][256 * 64];
  __shared__ int   tokS[128];
  __shared__ float gateS[128];

  const int tid = threadIdx.x;
  if (tid < 128) {
    int r = m0 + tid;
    bool v = (r < cnt);
    tokS[tid]  = v ? row_token[pairBase + r] : 0;
    gateS[tid] = v ? row_gate[pairBase + r] : 0.f;
  }
  __syncthreads();

  const int lane = tid & 63;
  const int wave = tid >> 6;
  const int quad = lane >> 4;
  const int l16  = lane & 15;
  const int lr   = lane >> 3;
  const int lc   = lane & 7;
  const int sw   = lc ^ lr;
  const int wr   = wave >> 2;
  const int wc   = wave & 3;

  const unsigned short* W2e = W2b + (size_t)e * D * F;
  const unsigned short* aSrc[2];
  const unsigned short* bSrc[4];
#pragma unroll
  for (int i = 0; i < 2; ++i) {
    int rA = i * 64 + wave * 8 + lr;
    int g = pairBase + m0 + rA;
    if (g > totalPairs - 1) g = totalPairs - 1;   // clamp: stay inside a_buf
    aSrc[i] = a_buf + (size_t)g * F + sw * 8;
  }
#pragma unroll
  for (int i = 0; i < 4; ++i) {
    int rB = i * 64 + wave * 8 + lr;
    bSrc[i] = W2e + (size_t)(bx * 256 + rB) * F + sw * 8;
  }

  auto stage = [&](int t, int b) {
#pragma unroll
    for (int i = 0; i < 2; ++i)
      load_lds16(aSrc[i] + t * 64, &As[b][(i * 64 + wave * 8) * 64]);
#pragma unroll
    for (int i = 0; i < 4; ++i)
      load_lds16(bSrc[i] + t * 64, &Bs[b][(i * 64 + wave * 8) * 64]);
  };

  f32x4 acc[4][4];
#pragma unroll
  for (int i = 0; i < 4; ++i)
#pragma unroll
    for (int j = 0; j < 4; ++j) acc[i][j] = (f32x4){0.f, 0.f, 0.f, 0.f};

  constexpr int NT = F / 64;   // 32
  stage(0, 0);
  stage(1, 1);
  int buf = 0;
  for (int t = 0; t < NT; ++t) {
    if (t + 2 < NT) {
      int nb = buf + 2; if (nb >= 3) nb -= 3;
      stage(t + 2, nb);
      asm volatile("s_waitcnt vmcnt(12)" ::: "memory");
    } else if (t + 1 < NT) {
      asm volatile("s_waitcnt vmcnt(6)" ::: "memory");
    } else {
      asm volatile("s_waitcnt vmcnt(0)" ::: "memory");
    }
    __builtin_amdgcn_sched_barrier(0);
    __builtin_amdgcn_s_barrier();
    __builtin_amdgcn_sched_barrier(0);
    const unsigned short* Ab = As[buf];
    const unsigned short* Bb = Bs[buf];
    bf16x8 a0[4], b0[4], a1[4], b1f[4];
#pragma unroll
    for (int i = 0; i < 4; ++i) a0[i]  = *frag_addr(Ab, wr * 64 + i * 16 + l16, 0,  quad);
#pragma unroll
    for (int j = 0; j < 4; ++j) b0[j]  = *frag_addr(Bb, wc * 64 + j * 16 + l16, 0,  quad);
#pragma unroll
    for (int i = 0; i < 4; ++i) a1[i]  = *frag_addr(Ab, wr * 64 + i * 16 + l16, 32, quad);
#pragma unroll
    for (int j = 0; j < 4; ++j) b1f[j] = *frag_addr(Bb, wc * 64 + j * 16 + l16, 32, quad);
    __builtin_amdgcn_s_setprio(1);
#pragma unroll
    for (int i = 0; i < 4; ++i)
#pragma unroll
      for (int j = 0; j < 4; ++j)
        acc[i][j] = __builtin_amdgcn_mfma_f32_16x16x32_bf16(a0[i], b0[j], acc[i][j], 0, 0, 0);
#pragma unroll
    for (int i = 0; i < 4; ++i)
#pragma unroll
      for (int j = 0; j < 4; ++j)
        acc[i][j] = __builtin_amdgcn_mfma_f32_16x16x32_bf16(a1[i], b1f[j], acc[i][j], 0, 0, 0);
    __builtin_amdgcn_s_setprio(0);
    __builtin_amdgcn_sched_barrier(0);
    __builtin_amdgcn_s_barrier();
    ++buf; if (buf >= 3) buf = 0;
  }

#pragma unroll
  for (int j = 0; j < 4; ++j) {
    int col = bx * 256 + wc * 64 + j * 16 + l16;
    float b2v = b2[e * D + col];
#pragma unroll
    for (int i = 0; i < 4; ++i) {
      int rb = wr * 64 + i * 16 + quad * 4;
#pragma unroll
      for (int rg = 0; rg < 4; ++rg) {
        int r = rb + rg;
        if (m0 + r < cnt) {
          float y = (acc[i][j][rg] + b2v) * gateS[r];
          atomicAdd(&out[(size_t)tokS[r] * D + col], y);
        }
      }
    }
  }
}

}  // namespace

extern "C" void kernel_launch(void* const* d_in, const int* in_sizes, int n_in,
                              void* d_out, int out_size, void* d_ws, size_t ws_size,
                              hipStream_t stream) {
  (void)n_in; (void)out_size; (void)ws_size;
  const float* x    = (const float*)d_in[0];
  const float* Wr   = (const float*)d_in[1];
  const float* temp = (const float*)d_in[2];
  const float* W1   = (const float*)d_in[3];
  const float* b1   = (const float*)d_in[4];
  const float* W2   = (const float*)d_in[5];
  const float* b2   = (const float*)d_in[6];
  float* out = (float*)d_out;
  const int T = in_sizes[0] / D;   // 4096

  // workspace layout (~137 MB)
  char* ws = (char*)d_ws;
  size_t off = 0;
  unsigned short* xb    = (unsigned short*)(ws + off); off += (size_t)T * D * 2;
  unsigned short* W1b   = (unsigned short*)(ws + off); off += (size_t)E * TWO_F * D * 2;
  unsigned short* W2b   = (unsigned short*)(ws + off); off += (size_t)E * D * F * 2;
  unsigned short* a_buf = (unsigned short*)(ws + off); off += (size_t)T * 2 * F * 2;
  int*   counts    = (int*)(ws + off); off += 64;
  int*   offsets   = (int*)(ws + off); off += 64;
  int*   topk_idx  = (int*)(ws + off); off += (size_t)T * 2 * 4;
  float* topk_gate = (float*)(ws + off); off += (size_t)T * 2 * 4;
  int*   row_token = (int*)(ws + off); off += (size_t)T * 2 * 4;
  float* row_gate  = (float*)(ws + off); off += (size_t)T * 2 * 4;

  const long long nx = (long long)T * D;
  const long long n1 = (long long)E * TWO_F * D;
  const long long n2 = (long long)E * D * F;

  zero_kernel<<<(T * D / 4 + 255) / 256, 256, 0, stream>>>(out, T * D / 4);
  router_kernel<<<(T + 3) / 4, 256, 0, stream>>>(x, Wr, temp, topk_idx, topk_gate, T);
  assign_kernel<<<1, 1024, 0, stream>>>(topk_idx, topk_gate, counts, offsets,
                                        row_token, row_gate, T);
  cvt_all_kernel<<<(int)((nx + n1 + n2) / 2048), 256, 0, stream>>>(x, W1, W2, xb, W1b, W2b,
                                                                   nx, n1);
  // per-expert cnt <= T = 4096 -> at BM=128, 32 m-tiles suffice
  gemm1_kernel<<<dim3(F / 128, 32, E), 512, 0, stream>>>(xb, W1b, b1, counts,
                                                         offsets, row_token, a_buf);
  gemm2_kernel<<<dim3(D / 256, 32, E), 512, 0, stream>>>(a_buf, W2b, b2, counts,
                                                         offsets, row_token,
                                                         row_gate, out, T * 2);
}

// Round 5
// 530.668 us; speedup vs baseline: 1.0684x; 1.0684x over previous
//
#include <hip/hip_runtime.h>
#include <hip/hip_bf16.h>

#define DEV __device__ __forceinline__

namespace {

constexpr int D     = 1024;
constexpr int F     = 2048;
constexpr int E     = 8;
constexpr int TWO_F = 2 * F;

typedef short bf16x8 __attribute__((ext_vector_type(8)));
typedef float f32x4  __attribute__((ext_vector_type(4)));

DEV unsigned short f32_to_bf16(float f) {
  unsigned int u = __builtin_bit_cast(unsigned int, f);
  u += 0x7fffu + ((u >> 16) & 1u);   // RNE
  return (unsigned short)(u >> 16);
}

// async global->LDS, 16B per lane; LDS dest is wave-uniform base + lane*16 implicit
DEV void load_lds16(const void* g, void* l) {
  __builtin_amdgcn_global_load_lds((const __attribute__((address_space(1))) void*)g,
                                   (__attribute__((address_space(3))) void*)l, 16, 0, 0);
}

// XOR-swizzled fragment address: LDS[row][c] holds global chunk c ^ (row&7).
DEV const bf16x8* frag_addr(const unsigned short* S, int row, int kk, int quad) {
  int cl = (((kk >> 3) + quad) ^ (row & 7));
  return (const bf16x8*)(S + row * 64 + cl * 8);
}

__global__ void zero_kernel(float* __restrict__ p, int n4) {
  int i = blockIdx.x * 256 + threadIdx.x;
  if (i < n4) ((float4*)p)[i] = make_float4(0.f, 0.f, 0.f, 0.f);
}

// One fused fp32->bf16 conversion over x, W1, W2 (sizes are multiples of 2048 elems).
__global__ void cvt_all_kernel(const float* __restrict__ x, const float* __restrict__ W1,
                               const float* __restrict__ W2,
                               unsigned short* __restrict__ xb, unsigned short* __restrict__ W1b,
                               unsigned short* __restrict__ W2b,
                               long long nx, long long n1) {
  long long i = (long long)(blockIdx.x * 256 + threadIdx.x) * 8;
  const float* src;
  unsigned short* dst;
  long long off;
  if (i < nx)            { src = x;  dst = xb;  off = i; }
  else if (i < nx + n1)  { src = W1; dst = W1b; off = i - nx; }
  else                   { src = W2; dst = W2b; off = i - nx - n1; }
  float4 a = *(const float4*)(src + off);
  float4 b = *(const float4*)(src + off + 4);
  uint4 o;
  o.x = (unsigned)f32_to_bf16(a.x) | ((unsigned)f32_to_bf16(a.y) << 16);
  o.y = (unsigned)f32_to_bf16(a.z) | ((unsigned)f32_to_bf16(a.w) << 16);
  o.z = (unsigned)f32_to_bf16(b.x) | ((unsigned)f32_to_bf16(b.y) << 16);
  o.w = (unsigned)f32_to_bf16(b.z) | ((unsigned)f32_to_bf16(b.w) << 16);
  *(uint4*)(dst + off) = o;
}

// Router: one wave per token; fp32 dot over D=1024, top-2 + softmax. NO atomics.
__global__ void router_kernel(const float* __restrict__ x, const float* __restrict__ Wr,
                              const float* __restrict__ temp,
                              int* __restrict__ topk_idx, float* __restrict__ topk_gate, int T) {
  int wid  = blockIdx.x * 4 + (threadIdx.x >> 6);
  int lane = threadIdx.x & 63;
  if (wid >= T) return;
  const float* xr = x + (size_t)wid * D;
  float acc[E];
#pragma unroll
  for (int e = 0; e < E; ++e) acc[e] = 0.f;
  int base = lane * 16;
#pragma unroll
  for (int u = 0; u < 4; ++u) {
    float4 xv = *(const float4*)(xr + base + u * 4);
#pragma unroll
    for (int e = 0; e < E; ++e) {
      float4 wv = *(const float4*)(Wr + e * D + base + u * 4);
      acc[e] += xv.x * wv.x + xv.y * wv.y + xv.z * wv.z + xv.w * wv.w;
    }
  }
#pragma unroll
  for (int e = 0; e < E; ++e) {
    float v = acc[e];
#pragma unroll
    for (int off = 32; off > 0; off >>= 1) v += __shfl_xor(v, off, 64);
    acc[e] = v;
  }
  if (lane == 0) {
    float inv = 1.0f / temp[0];
    float l[E];
#pragma unroll
    for (int e = 0; e < E; ++e) l[e] = acc[e] * inv;
    int e0 = 0;
#pragma unroll
    for (int e = 1; e < E; ++e) if (l[e] > l[e0]) e0 = e;   // first-index tie-break like top_k
    int e1 = (e0 == 0) ? 1 : 0;
#pragma unroll
    for (int e = 0; e < E; ++e) if (e != e0 && l[e] > l[e1]) e1 = e;
    float dlt = l[e1] - l[e0];
    float ed  = __expf(dlt);
    topk_idx[2 * wid]      = e0;
    topk_idx[2 * wid + 1]  = e1;
    topk_gate[2 * wid]     = 1.f / (1.f + ed);
    topk_gate[2 * wid + 1] = ed / (1.f + ed);
  }
}

// Single block, 1024 threads: histogram (LDS atomics) -> scan -> compacted expert lists.
__global__ __launch_bounds__(1024)
void assign_kernel(const int* __restrict__ topk_idx, const float* __restrict__ topk_gate,
                   int* __restrict__ counts, int* __restrict__ offsets,
                   int* __restrict__ row_token, float* __restrict__ row_gate, int T) {
  __shared__ int hist[E];
  __shared__ int cur[E];
  const int tid = threadIdx.x;
  if (tid < E) hist[tid] = 0;
  __syncthreads();
  for (int t = tid; t < T; t += 1024) {
    atomicAdd(&hist[topk_idx[2 * t]], 1);
    atomicAdd(&hist[topk_idx[2 * t + 1]], 1);
  }
  __syncthreads();
  if (tid == 0) {
    int s = 0;
    for (int e = 0; e < E; ++e) {
      int c = hist[e];
      counts[e]  = c;
      offsets[e] = s;
      cur[e]     = s;
      s += c;
    }
  }
  __syncthreads();
  for (int t = tid; t < T; t += 1024) {
#pragma unroll
    for (int s = 0; s < 2; ++s) {
      int e = topk_idx[2 * t + s];
      int p = atomicAdd(&cur[e], 1);
      row_token[p] = t;
      row_gate[p]  = topk_gate[2 * t + s];
    }
  }
}

// ---------------------------------------------------------------------------
// GEMM structure (known-good geometry + counted-vmcnt double buffer):
// 256 thr / 2x2 waves; tile 128 x (64|128); BK=64; As/Bs 2 x 16 KB each
// (66 KB LDS -> 2 blocks/CU, independent barrier groups cover stalls).
// Per K-tile: issue stage(t+1) into buf^1 (8 gload_lds/wave), then
// s_waitcnt vmcnt(8) (tile-t landed, t+1 in flight), raw s_barrier, compute
// tile t, raw s_barrier, flip.  No vmcnt(0) drain in the main loop.
// Race-freedom: barrier#2 of iter t-1 orders all reads of buf^1 before
// stage(t+1) writes it; per-wave vmcnt + barrier#1 orders landings before
// reads.  Control flow around barriers is block-uniform; vmcnt waits are
// monotonically satisfiable (no deadlock path).
// ---------------------------------------------------------------------------

// GEMM1: h = gather(x) @ W1[e]^T; fused SwiGLU -> a_buf (bf16).
// Bs row grouping: [h1 c0..31 | h2 c0..31 | h1 c32..63 | h2 c32..63];
// acc[i][j] (j=0,1 -> h1) pairs acc[i][j+2] (h2).
__global__ __launch_bounds__(256, 2)
void gemm1_kernel(const unsigned short* __restrict__ xb,
                  const unsigned short* __restrict__ W1b,
                  const float* __restrict__ b1,
                  const int* __restrict__ counts, const int* __restrict__ offsets,
                  const int* __restrict__ row_token,
                  unsigned short* __restrict__ a_buf) {
  const int e  = blockIdx.z;
  const int m0 = blockIdx.y * 128;
  const int n0 = blockIdx.x * 64;
  const int cnt = counts[e];
  if (m0 >= cnt) return;
  const int pairBase = offsets[e];

  __shared__ __align__(16) unsigned short As[2][128 * 64];
  __shared__ __align__(16) unsigned short Bs[2][128 * 64];
  __shared__ int tokS[128];

  const int tid = threadIdx.x;
  if (tid < 128) {
    int r = m0 + tid;
    tokS[tid] = (r < cnt) ? row_token[pairBase + r] : row_token[pairBase];  // clamp: safe garbage
  }
  __syncthreads();

  const int lane = tid & 63;
  const int wave = tid >> 6;
  const int quad = lane >> 4;
  const int l16  = lane & 15;
  const int lr   = lane >> 3;
  const int lc   = lane & 7;
  const int sw   = lc ^ lr;            // pre-swizzled global chunk
  const int wr   = wave >> 1;
  const int wc   = wave & 1;

  const unsigned short* W1e = W1b + (size_t)e * TWO_F * D;
  const unsigned short* aptr[4];
  const unsigned short* bptr[4];
#pragma unroll
  for (int i = 0; i < 4; ++i) {
    int r = wave * 32 + i * 8 + lr;
    aptr[i] = xb + (size_t)tokS[r] * D + sw * 8;
    int g = r >> 5, s = r & 31;
    int wrow = (g & 1) * F + n0 + (g >> 1) * 32 + s;
    bptr[i] = W1e + (size_t)wrow * D + sw * 8;
  }

  auto stage = [&](int t, int b) {
#pragma unroll
    for (int i = 0; i < 4; ++i)
      load_lds16(aptr[i] + t * 64, &As[b][(wave * 32 + i * 8) * 64]);
#pragma unroll
    for (int i = 0; i < 4; ++i)
      load_lds16(bptr[i] + t * 64, &Bs[b][(wave * 32 + i * 8) * 64]);
  };

  f32x4 acc[4][4];
#pragma unroll
  for (int i = 0; i < 4; ++i)
#pragma unroll
    for (int j = 0; j < 4; ++j) acc[i][j] = (f32x4){0.f, 0.f, 0.f, 0.f};

  constexpr int NT = D / 64;   // 16
  stage(0, 0);
  int buf = 0;
  for (int t = 0; t < NT; ++t) {
    if (t + 1 < NT) {
      stage(t + 1, buf ^ 1);
      asm volatile("s_waitcnt vmcnt(8)" ::: "memory");   // own tile-t loads landed
    } else {
      asm volatile("s_waitcnt vmcnt(0)" ::: "memory");
    }
    __builtin_amdgcn_sched_barrier(0);
    __builtin_amdgcn_s_barrier();          // all waves' tile-t loads landed
    __builtin_amdgcn_sched_barrier(0);
    const unsigned short* Ab = As[buf];
    const unsigned short* Bb = Bs[buf];
#pragma unroll
    for (int kk = 0; kk < 64; kk += 32) {
      bf16x8 af[4], bf[4];
#pragma unroll
      for (int i = 0; i < 4; ++i)
        af[i] = *frag_addr(Ab, wr * 64 + i * 16 + l16, kk, quad);
#pragma unroll
      for (int j = 0; j < 4; ++j)
        bf[j] = *frag_addr(Bb, wc * 64 + j * 16 + l16, kk, quad);
#pragma unroll
      for (int i = 0; i < 4; ++i)
#pragma unroll
        for (int j = 0; j < 4; ++j)
          acc[i][j] = __builtin_amdgcn_mfma_f32_16x16x32_bf16(af[i], bf[j], acc[i][j], 0, 0, 0);
    }
    __builtin_amdgcn_sched_barrier(0);
    __builtin_amdgcn_s_barrier();          // reads of buf done -> safe to overwrite next iter
    buf ^= 1;
  }

  // Epilogue: a = h1 * silu(h2).
#pragma unroll
  for (int i = 0; i < 4; ++i) {
    int rb = wr * 64 + i * 16 + quad * 4;
#pragma unroll
    for (int j = 0; j < 2; ++j) {
      int col = n0 + wc * 32 + j * 16 + l16;
      float bh1 = b1[e * TWO_F + col];
      float bh2 = b1[e * TWO_F + F + col];
#pragma unroll
      for (int rg = 0; rg < 4; ++rg) {
        int r = rb + rg;
        if (m0 + r < cnt) {
          float h1 = acc[i][j][rg] + bh1;
          float h2 = acc[i][j + 2][rg] + bh2;
          float a  = h1 * (h2 / (1.f + __expf(-h2)));
          a_buf[(size_t)(pairBase + m0 + r) * F + col] = f32_to_bf16(a);
        }
      }
    }
  }
}

// GEMM2: y = a @ W2[e]^T ; out[token] += gate * (y + b2)  (fp32 atomics, out pre-zeroed)
__global__ __launch_bounds__(256, 2)
void gemm2_kernel(const unsigned short* __restrict__ a_buf,
                  const unsigned short* __restrict__ W2b,
                  const float* __restrict__ b2,
                  const int* __restrict__ counts, const int* __restrict__ offsets,
                  const int* __restrict__ row_token, const float* __restrict__ row_gate,
                  float* __restrict__ out, int totalPairs) {
  const int e  = blockIdx.z;
  const int m0 = blockIdx.y * 128;
  const int n0 = blockIdx.x * 128;
  const int cnt = counts[e];
  if (m0 >= cnt) return;
  const int pairBase = offsets[e];

  __shared__ __align__(16) unsigned short As[2][128 * 64];
  __shared__ __align__(16) unsigned short Bs[2][128 * 64];
  __shared__ int   tokS[128];
  __shared__ float gateS[128];

  const int tid = threadIdx.x;
  if (tid < 128) {
    int r = m0 + tid;
    bool v = (r < cnt);
    tokS[tid]  = v ? row_token[pairBase + r] : 0;
    gateS[tid] = v ? row_gate[pairBase + r] : 0.f;
  }
  __syncthreads();

  const int lane = tid & 63;
  const int wave = tid >> 6;
  const int quad = lane >> 4;
  const int l16  = lane & 15;
  const int lr   = lane >> 3;
  const int lc   = lane & 7;
  const int sw   = lc ^ lr;
  const int wr   = wave >> 1;
  const int wc   = wave & 1;

  const unsigned short* W2e = W2b + (size_t)e * D * F;
  const unsigned short* aptr[4];
  const unsigned short* bptr[4];
#pragma unroll
  for (int i = 0; i < 4; ++i) {
    int r = wave * 32 + i * 8 + lr;
    int g = pairBase + m0 + r;
    if (g > totalPairs - 1) g = totalPairs - 1;   // clamp: stay inside a_buf
    aptr[i] = a_buf + (size_t)g * F + sw * 8;
    bptr[i] = W2e + (size_t)(n0 + r) * F + sw * 8;
  }

  auto stage = [&](int t, int b) {
#pragma unroll
    for (int i = 0; i < 4; ++i)
      load_lds16(aptr[i] + t * 64, &As[b][(wave * 32 + i * 8) * 64]);
#pragma unroll
    for (int i = 0; i < 4; ++i)
      load_lds16(bptr[i] + t * 64, &Bs[b][(wave * 32 + i * 8) * 64]);
  };

  f32x4 acc[4][4];
#pragma unroll
  for (int i = 0; i < 4; ++i)
#pragma unroll
    for (int j = 0; j < 4; ++j) acc[i][j] = (f32x4){0.f, 0.f, 0.f, 0.f};

  constexpr int NT = F / 64;   // 32
  stage(0, 0);
  int buf = 0;
  for (int t = 0; t < NT; ++t) {
    if (t + 1 < NT) {
      stage(t + 1, buf ^ 1);
      asm volatile("s_waitcnt vmcnt(8)" ::: "memory");
    } else {
      asm volatile("s_waitcnt vmcnt(0)" ::: "memory");
    }
    __builtin_amdgcn_sched_barrier(0);
    __builtin_amdgcn_s_barrier();
    __builtin_amdgcn_sched_barrier(0);
    const unsigned short* Ab = As[buf];
    const unsigned short* Bb = Bs[buf];
#pragma unroll
    for (int kk = 0; kk < 64; kk += 32) {
      bf16x8 af[4], bf[4];
#pragma unroll
      for (int i = 0; i < 4; ++i)
        af[i] = *frag_addr(Ab, wr * 64 + i * 16 + l16, kk, quad);
#pragma unroll
      for (int j = 0; j < 4; ++j)
        bf[j] = *frag_addr(Bb, wc * 64 + j * 16 + l16, kk, quad);
#pragma unroll
      for (int i = 0; i < 4; ++i)
#pragma unroll
        for (int j = 0; j < 4; ++j)
          acc[i][j] = __builtin_amdgcn_mfma_f32_16x16x32_bf16(af[i], bf[j], acc[i][j], 0, 0, 0);
    }
    __builtin_amdgcn_sched_barrier(0);
    __builtin_amdgcn_s_barrier();
    buf ^= 1;
  }

#pragma unroll
  for (int j = 0; j < 4; ++j) {
    int col = n0 + wc * 64 + j * 16 + l16;
    float b2v = b2[e * D + col];
#pragma unroll
    for (int i = 0; i < 4; ++i) {
      int rb = wr * 64 + i * 16 + quad * 4;
#pragma unroll
      for (int rg = 0; rg < 4; ++rg) {
        int r = rb + rg;
        if (m0 + r < cnt) {
          float y = (acc[i][j][rg] + b2v) * gateS[r];
          atomicAdd(&out[(size_t)tokS[r] * D + col], y);
        }
      }
    }
  }
}

}  // namespace

extern "C" void kernel_launch(void* const* d_in, const int* in_sizes, int n_in,
                              void* d_out, int out_size, void* d_ws, size_t ws_size,
                              hipStream_t stream) {
  (void)n_in; (void)out_size; (void)ws_size;
  const float* x    = (const float*)d_in[0];
  const float* Wr   = (const float*)d_in[1];
  const float* temp = (const float*)d_in[2];
  const float* W1   = (const float*)d_in[3];
  const float* b1   = (const float*)d_in[4];
  const float* W2   = (const float*)d_in[5];
  const float* b2   = (const float*)d_in[6];
  float* out = (float*)d_out;
  const int T = in_sizes[0] / D;   // 4096

  // workspace layout (~137 MB)
  char* ws = (char*)d_ws;
  size_t off = 0;
  unsigned short* xb    = (unsigned short*)(ws + off); off += (size_t)T * D * 2;
  unsigned short* W1b   = (unsigned short*)(ws + off); off += (size_t)E * TWO_F * D * 2;
  unsigned short* W2b   = (unsigned short*)(ws + off); off += (size_t)E * D * F * 2;
  unsigned short* a_buf = (unsigned short*)(ws + off); off += (size_t)T * 2 * F * 2;
  int*   counts    = (int*)(ws + off); off += 64;
  int*   offsets   = (int*)(ws + off); off += 64;
  int*   topk_idx  = (int*)(ws + off); off += (size_t)T * 2 * 4;
  float* topk_gate = (float*)(ws + off); off += (size_t)T * 2 * 4;
  int*   row_token = (int*)(ws + off); off += (size_t)T * 2 * 4;
  float* row_gate  = (float*)(ws + off); off += (size_t)T * 2 * 4;

  const long long nx = (long long)T * D;
  const long long n1 = (long long)E * TWO_F * D;
  const long long n2 = (long long)E * D * F;

  zero_kernel<<<(T * D / 4 + 255) / 256, 256, 0, stream>>>(out, T * D / 4);
  router_kernel<<<(T + 3) / 4, 256, 0, stream>>>(x, Wr, temp, topk_idx, topk_gate, T);
  assign_kernel<<<1, 1024, 0, stream>>>(topk_idx, topk_gate, counts, offsets,
                                        row_token, row_gate, T);
  cvt_all_kernel<<<(int)((nx + n1 + n2) / 2048), 256, 0, stream>>>(x, W1, W2, xb, W1b, W2b,
                                                                   nx, n1);
  // per-expert cnt <= T = 4096 -> at BM=128, 32 m-tiles suffice
  gemm1_kernel<<<dim3(F / 64, 32, E), 256, 0, stream>>>(xb, W1b, b1, counts,
                                                        offsets, row_token, a_buf);
  gemm2_kernel<<<dim3(D / 128, 32, E), 256, 0, stream>>>(a_buf, W2b, b2, counts,
                                                         offsets, row_token,
                                                         row_gate, out, T * 2);
}